// Round 2
// baseline (177.916 us; speedup 1.0000x reference)
//
#include <hip/hip_runtime.h>
#include <hip/hip_bf16.h>

#define N_NODES 16000
#define IN_F 128
#define HID 64
#define BATCH 32
#define NPAIR 128
#define DRES 100
#define NCLS 10

// workspace layout (float offsets)
#define NF_OFF    0
#define IMGS_OFF  16000                      // [32][2][100][100]
#define POOL1_OFF (16000 + 640000)           // [32][16][50][50]
#define POOL2_OFF (16000 + 640000 + 1280000) // [32][32][25][25]

// ---------------- Kernel A: node filtration MLP ----------------
// one wave per node: lane j computes hidden unit j, then wave-reduce for w2 dot.
__global__ __launch_bounds__(256) void k_filt(const float* __restrict__ x,
    const float* __restrict__ w1, const float* __restrict__ b1,
    const float* __restrict__ w2, const float* __restrict__ b2,
    float* __restrict__ nf, float* __restrict__ out_nf)
{
    int t = threadIdx.x;
    int wave = t >> 6, lane = t & 63;
    int n = blockIdx.x * 4 + wave;
    if (n >= N_NODES) return;
    const float* xr = x + (size_t)n * IN_F;
    float acc = b1[lane];
    #pragma unroll 8
    for (int k = 0; k < IN_F; ++k)
        acc += xr[k] * w1[k * HID + lane];
    float h = fmaxf(acc, 0.f);
    float p = h * w2[lane];
    #pragma unroll
    for (int off = 32; off > 0; off >>= 1)
        p += __shfl_down(p, off, 64);
    if (lane == 0) {
        float s = p + b2[0];
        float f = 1.f / (1.f + expf(-s));
        nf[n] = f;
        out_nf[n] = f;
    }
}

// ---------------- Kernel B: persistence image ----------------
// one block per (batch, channel). Separable Gaussian outer-product accumulation.
// thread t<169: (ti,tj) = (t/13, t%13); owns cells i = ti+13r, j = tj+13s, r,s in 0..7.
// normalization: im/im.max — the 1/(2*pi*VAR) constant cancels, omitted.
// exp(-g/(2*VAR)) with VAR=0.5 -> exp(-g) = exp(-db^2)*exp(-dp^2) (separable).
__global__ __launch_bounds__(256) void k_pimg(const float* __restrict__ nf,
    const int* __restrict__ pi0, const int* __restrict__ pi1,
    float* __restrict__ imgs)
{
    int b = blockIdx.x >> 1, c = blockIdx.x & 1;
    const int* pi = c ? pi1 : pi0;
    __shared__ float sb[NPAIR], sp[NPAIR];
    __shared__ float wmax[4];
    int t = threadIdx.x;
    if (t < NPAIR) {
        int i0 = pi[(b * NPAIR + t) * 2 + 0];
        int i1 = pi[(b * NPAIR + t) * 2 + 1];
        float f0 = nf[i0], f1 = nf[i1];
        sb[t] = f0;          // birth
        sp[t] = f1 - f0;     // persistence
    }
    __syncthreads();

    int ti = t / 13, tj = t % 13;
    float ci[8], cj[8];
    #pragma unroll
    for (int r = 0; r < 8; ++r) {
        ci[r] = (float)(ti + 13 * r) * 0.01f;
        cj[r] = (float)(tj + 13 * r) * 0.01f;
    }
    float acc[8][8];
    #pragma unroll
    for (int r = 0; r < 8; ++r)
        #pragma unroll
        for (int s = 0; s < 8; ++s) acc[r][s] = 0.f;

    for (int p = 0; p < NPAIR; ++p) {
        float bb = sb[p], pp = sp[p];
        float eb[8], ep[8];
        #pragma unroll
        for (int r = 0; r < 8; ++r) {
            float d = bb - ci[r];
            eb[r] = __expf(-d * d);
        }
        #pragma unroll
        for (int s = 0; s < 8; ++s) {
            float d = pp - cj[s];
            ep[s] = __expf(-d * d);
        }
        #pragma unroll
        for (int r = 0; r < 8; ++r)
            #pragma unroll
            for (int s = 0; s < 8; ++s)
                acc[r][s] += eb[r] * ep[s];
    }

    bool active = t < 169;
    float lmax = 0.f;
    if (active) {
        #pragma unroll
        for (int r = 0; r < 8; ++r) {
            if (ti + 13 * r < DRES) {
                #pragma unroll
                for (int s = 0; s < 8; ++s)
                    if (tj + 13 * s < DRES) lmax = fmaxf(lmax, acc[r][s]);
            }
        }
    }
    #pragma unroll
    for (int off = 32; off > 0; off >>= 1)
        lmax = fmaxf(lmax, __shfl_xor(lmax, off, 64));
    if ((t & 63) == 0) wmax[t >> 6] = lmax;
    __syncthreads();
    float bmax = fmaxf(fmaxf(wmax[0], wmax[1]), fmaxf(wmax[2], wmax[3]));
    float inv = 1.f / bmax;
    if (active) {
        float* dst = imgs + (size_t)(b * 2 + c) * DRES * DRES;
        #pragma unroll
        for (int r = 0; r < 8; ++r) {
            int i = ti + 13 * r;
            if (i < DRES) {
                #pragma unroll
                for (int s = 0; s < 8; ++s) {
                    int j = tj + 13 * s;
                    if (j < DRES) dst[i * DRES + j] = acc[r][s] * inv;
                }
            }
        }
    }
}

// ---------------- Kernel C: conv1 (2->16, 5x5, pad2) + relu + maxpool2 ----------------
// block per (b, pooled row oh). 200 active threads: (ow in 50) x (ocg in 4, 4 oc each).
__global__ __launch_bounds__(256) void k_conv1(const float* __restrict__ imgs,
    const float* __restrict__ cw, const float* __restrict__ cb,
    float* __restrict__ pool1)
{
    int bx = blockIdx.x;
    int b = bx / 50, oh = bx % 50;
    __shared__ float in_[2][6][104];
    __shared__ float wgt[800];
    __shared__ float bias[16];
    int t = threadIdx.x;
    for (int idx = t; idx < 800; idx += 256) wgt[idx] = cw[idx];
    if (t < 16) bias[t] = cb[t];
    for (int idx = t; idx < 2 * 6 * 104; idx += 256) {
        int ic = idx / 624, rem = idx % 624;
        int r = rem / 104, cc = rem % 104;
        int iy = 2 * oh - 2 + r, ix = cc - 2;
        float v = 0.f;
        if (iy >= 0 && iy < 100 && ix >= 0 && ix < 100)
            v = imgs[((size_t)(b * 2 + ic) * 100 + iy) * 100 + ix];
        in_[ic][r][cc] = v;
    }
    __syncthreads();
    if (t >= 200) return;
    int ow = t % 50, ocg = t / 50;
    int oc0 = ocg * 4;
    float acc[4][2][2] = {};
    for (int ic = 0; ic < 2; ++ic) {
        float patch[6][6];
        #pragma unroll
        for (int r = 0; r < 6; ++r)
            #pragma unroll
            for (int k = 0; k < 6; ++k)
                patch[r][k] = in_[ic][r][2 * ow + k];
        #pragma unroll
        for (int o = 0; o < 4; ++o) {
            const float* w = &wgt[((oc0 + o) * 2 + ic) * 25];
            #pragma unroll
            for (int kh = 0; kh < 5; ++kh)
                #pragma unroll
                for (int kw = 0; kw < 5; ++kw) {
                    float wv = w[kh * 5 + kw];
                    acc[o][0][0] += patch[kh][kw] * wv;
                    acc[o][0][1] += patch[kh][kw + 1] * wv;
                    acc[o][1][0] += patch[kh + 1][kw] * wv;
                    acc[o][1][1] += patch[kh + 1][kw + 1] * wv;
                }
        }
    }
    #pragma unroll
    for (int o = 0; o < 4; ++o) {
        float m = fmaxf(fmaxf(acc[o][0][0], acc[o][0][1]),
                        fmaxf(acc[o][1][0], acc[o][1][1]));
        float res = fmaxf(m + bias[oc0 + o], 0.f);
        pool1[((size_t)(b * 16 + oc0 + o) * 50 + oh) * 50 + ow] = res;
    }
}

// ---------------- Kernel D: conv2 (16->32, 5x5, pad2) + relu + maxpool2 ----------------
// block per (b, pooled row oh in 25). 200 active threads: (ow in 25) x (ocg in 8, 4 oc each).
__global__ __launch_bounds__(256) void k_conv2(const float* __restrict__ pool1,
    const float* __restrict__ cw, const float* __restrict__ cb,
    float* __restrict__ pool2)
{
    int bx = blockIdx.x;
    int b = bx / 25, oh = bx % 25;
    __shared__ float in_[16][6][54];
    int t = threadIdx.x;
    for (int idx = t; idx < 16 * 6 * 54; idx += 256) {
        int ic = idx / 324, rem = idx % 324;
        int r = rem / 54, cc = rem % 54;
        int iy = 2 * oh - 2 + r, ix = cc - 2;
        float v = 0.f;
        if (iy >= 0 && iy < 50 && ix >= 0 && ix < 50)
            v = pool1[((size_t)(b * 16 + ic) * 50 + iy) * 50 + ix];
        in_[ic][r][cc] = v;
    }
    __syncthreads();
    if (t >= 200) return;
    int ow = t % 25, ocg = t / 25;
    int oc0 = ocg * 4;
    float acc[4][2][2] = {};
    for (int ic = 0; ic < 16; ++ic) {
        float patch[6][6];
        #pragma unroll
        for (int r = 0; r < 6; ++r)
            #pragma unroll
            for (int k = 0; k < 6; ++k)
                patch[r][k] = in_[ic][r][2 * ow + k];
        #pragma unroll
        for (int o = 0; o < 4; ++o) {
            const float* w = cw + ((size_t)(oc0 + o) * 16 + ic) * 25;
            #pragma unroll
            for (int kh = 0; kh < 5; ++kh)
                #pragma unroll
                for (int kw = 0; kw < 5; ++kw) {
                    float wv = w[kh * 5 + kw];
                    acc[o][0][0] += patch[kh][kw] * wv;
                    acc[o][0][1] += patch[kh][kw + 1] * wv;
                    acc[o][1][0] += patch[kh + 1][kw] * wv;
                    acc[o][1][1] += patch[kh + 1][kw + 1] * wv;
                }
        }
    }
    #pragma unroll
    for (int o = 0; o < 4; ++o) {
        float m = fmaxf(fmaxf(acc[o][0][0], acc[o][0][1]),
                        fmaxf(acc[o][1][0], acc[o][1][1]));
        float res = fmaxf(m + cb[oc0 + o], 0.f);
        pool2[((size_t)(b * 32 + oc0 + o) * 25 + oh) * 25 + ow] = res;
    }
}

// ---------------- Kernel E: final linear [B,20000] @ out_w.T + out_b ----------------
// block per (b, cls)
__global__ __launch_bounds__(256) void k_fc(const float* __restrict__ pool2,
    const float* __restrict__ oww, const float* __restrict__ ob,
    float* __restrict__ yhat)
{
    int b = blockIdx.x / NCLS, cls = blockIdx.x % NCLS;
    int t = threadIdx.x;
    const float* y = pool2 + (size_t)b * 20000;
    const float* w = oww + (size_t)cls * 20000;
    float acc = 0.f;
    for (int k = t; k < 20000; k += 256)
        acc += y[k] * w[k];
    #pragma unroll
    for (int off = 32; off > 0; off >>= 1)
        acc += __shfl_down(acc, off, 64);
    __shared__ float part[4];
    if ((t & 63) == 0) part[t >> 6] = acc;
    __syncthreads();
    if (t == 0) {
        float s = part[0] + part[1] + part[2] + part[3] + ob[cls];
        yhat[b * NCLS + cls] = s;
    }
}

extern "C" void kernel_launch(void* const* d_in, const int* in_sizes, int n_in,
                              void* d_out, int out_size, void* d_ws, size_t ws_size,
                              hipStream_t stream)
{
    const float* x   = (const float*)d_in[0];
    const int*   pi0 = (const int*)d_in[1];
    const int*   pi1 = (const int*)d_in[2];
    const float* w1  = (const float*)d_in[3];
    const float* b1  = (const float*)d_in[4];
    const float* w2  = (const float*)d_in[5];
    const float* b2  = (const float*)d_in[6];
    const float* c1w = (const float*)d_in[7];
    const float* c1b = (const float*)d_in[8];
    const float* c2w = (const float*)d_in[9];
    const float* c2b = (const float*)d_in[10];
    const float* oww = (const float*)d_in[11];
    const float* owb = (const float*)d_in[12];
    float* out = (float*)d_out;
    float* ws = (float*)d_ws;

    float* nf    = ws + NF_OFF;
    float* imgs  = ws + IMGS_OFF;
    float* pool1 = ws + POOL1_OFF;
    float* pool2 = ws + POOL2_OFF;

    k_filt <<<4000, 256, 0, stream>>>(x, w1, b1, w2, b2, nf, out + BATCH * NCLS);
    k_pimg <<<BATCH * 2, 256, 0, stream>>>(nf, pi0, pi1, imgs);
    k_conv1<<<BATCH * 50, 256, 0, stream>>>(imgs, c1w, c1b, pool1);
    k_conv2<<<BATCH * 25, 256, 0, stream>>>(pool1, c2w, c2b, pool2);
    k_fc   <<<BATCH * NCLS, 256, 0, stream>>>(pool2, oww, owb, out);
}